// Round 1
// 756.998 us; speedup vs baseline: 1.1534x; 1.1534x over previous
//
#include <hip/hip_runtime.h>
#include <hip/hip_bf16.h>

#define N_NODES 50000
#define N_EDGES 800000
#define D 128
#define D2 64  // packed-uint (2×bf16) per row

static constexpr float SLOPE = 11.0f / 48.0f;  // eval-mode RReLU mean slope

typedef __attribute__((ext_vector_type(8))) short bf16x8;
typedef __attribute__((ext_vector_type(4))) float f32x4;
typedef __attribute__((ext_vector_type(2))) unsigned int u32x2;
typedef __attribute__((ext_vector_type(4))) unsigned int u32x4;

__device__ __forceinline__ float bf_lo(unsigned int v) { return __uint_as_float(v << 16); }
__device__ __forceinline__ float bf_hi(unsigned int v) { return __uint_as_float(v & 0xffff0000u); }

__device__ __forceinline__ unsigned short f2bf(float x) {
    __hip_bfloat16 b = __float2bfloat16(x);
    return *(unsigned short*)&b;
}

__device__ __forceinline__ unsigned int pack_bf2(float lo, float hi) {
    return ((unsigned int)f2bf(hi) << 16) | (unsigned int)f2bf(lo);
}

// ---------------- fp32 -> packed bf16 conversion (node_feats, weights) ----------------

__global__ void k_cvt_nf(const f32x4* __restrict__ in, u32x4* __restrict__ out) {
    int i = blockIdx.x * 256 + threadIdx.x;  // each thread: 8 floats
    if (i >= N_NODES * D / 8) return;
    f32x4 lo = in[2 * i];
    f32x4 hi = in[2 * i + 1];
    u32x4 o;
    o.x = pack_bf2(lo[0], lo[1]);
    o.y = pack_bf2(lo[2], lo[3]);
    o.z = pack_bf2(hi[0], hi[1]);
    o.w = pack_bf2(hi[2], hi[3]);
    out[i] = o;
}

// converts Wn0, Ws0, Wn1, Ws1 (each 128x128 fp32) into one packed bf16 buffer
__global__ void k_cvt_w(const float* __restrict__ Wn0, const float* __restrict__ Ws0,
                        const float* __restrict__ Wn1, const float* __restrict__ Ws1,
                        unsigned int* __restrict__ out) {
    int i = blockIdx.x * 256 + threadIdx.x;  // 8192 threads total, 8 floats each
    int m = i >> 11;                         // matrix id
    int j = i & 2047;
    const float* W = (m == 0) ? Wn0 : (m == 1) ? Ws0 : (m == 2) ? Wn1 : Ws1;
    f32x4 lo = ((const f32x4*)W)[2 * j];
    f32x4 hi = ((const f32x4*)W)[2 * j + 1];
    u32x4 o;
    o.x = pack_bf2(lo[0], lo[1]);
    o.y = pack_bf2(lo[2], lo[3]);
    o.z = pack_bf2(hi[0], hi[1]);
    o.w = pack_bf2(hi[2], hi[3]);
    *(u32x4*)(out + (size_t)m * 8192 + 4 * j) = o;
}

// ---------------- CSR build ----------------

__global__ void k_count(const int* __restrict__ dst, int* __restrict__ deg) {
    int e = blockIdx.x * 256 + threadIdx.x;
    if (e < N_EDGES) atomicAdd(&deg[dst[e]], 1);
}

__global__ void k_scan1(const int* __restrict__ deg, int* __restrict__ offs,
                        int* __restrict__ part) {
    __shared__ int sm[256];
    int t = threadIdx.x;
    int i = blockIdx.x * 256 + t;
    int v = (i < N_NODES) ? deg[i] : 0;
    int orig = v;
    sm[t] = v;
    __syncthreads();
    for (int off = 1; off < 256; off <<= 1) {
        int x = (t >= off) ? sm[t - off] : 0;
        __syncthreads();
        sm[t] += x;
        __syncthreads();
    }
    if (i < N_NODES) offs[i] = sm[t] - orig;  // exclusive within block
    if (t == 255) part[blockIdx.x] = sm[t];   // block total
}

__global__ void k_scan2(int* __restrict__ part, int nb) {
    __shared__ int sm[256];
    int t = threadIdx.x;
    int v = (t < nb) ? part[t] : 0;
    int orig = v;
    sm[t] = v;
    __syncthreads();
    for (int off = 1; off < 256; off <<= 1) {
        int x = (t >= off) ? sm[t - off] : 0;
        __syncthreads();
        sm[t] += x;
        __syncthreads();
    }
    if (t < nb) part[t] = sm[t] - orig;  // exclusive block offsets
}

__global__ void k_scan3(int* __restrict__ offs, const int* __restrict__ part) {
    int i = blockIdx.x * 256 + threadIdx.x;
    if (i < N_NODES) offs[i] += part[blockIdx.x];
}

__global__ void k_fill(const int* __restrict__ src, const int* __restrict__ dst,
                       const int* __restrict__ offs, int* __restrict__ cur,
                       int2* __restrict__ csr) {
    int e = blockIdx.x * 256 + threadIdx.x;
    if (e < N_EDGES) {
        int d = dst[e];
        int p = offs[d] + atomicAdd(&cur[d], 1);
        csr[p] = make_int2(src[e], e);  // (src node, edge id)
    }
}

// iso-node list (deg==0); Poisson(16) degrees -> expected ~0 entries
__global__ void k_iso(const int* __restrict__ deg, int* __restrict__ isolist,
                      int* __restrict__ niso) {
    int i = blockIdx.x * 256 + threadIdx.x;
    if (i < N_NODES && deg[i] == 0) {
        int p = atomicAdd(niso, 1);
        isolist[p] = i;
    }
}

// ---------------- layer-1 aggregation: 2 edges/iteration ----------------
// half-wave (32 lanes) per edge; lane covers element group [4c, 4c+4).
// efsum[n] = sum edge_feats (bf16-packed, reused by layer 2)
// pre[n]   = (sum nf_bf16[src] + efsum[n]) / max(deg,1)   (bf16-packed)

__global__ void k_agg_ef(const unsigned int* __restrict__ nfb,  // bf16 [N*64]
                         const f32x4* __restrict__ ef,          // fp32 [E*32]
                         const int2* __restrict__ csr,
                         const int* __restrict__ offs, const int* __restrict__ deg,
                         unsigned int* __restrict__ efsum,
                         unsigned int* __restrict__ pre) {
    int node = blockIdx.x * 4 + (threadIdx.x >> 6);
    if (node >= N_NODES) return;
    int lane = threadIdx.x & 63;
    int half = lane >> 5;  // which edge of the pair this lane handles
    int c = lane & 31;     // element group [4c, 4c+4)
    int start = offs[node];
    int cnt = deg[node];
    f32x4 ae = {0.f, 0.f, 0.f, 0.f};
    f32x4 ah = {0.f, 0.f, 0.f, 0.f};
#pragma unroll 2
    for (int k = half; k < cnt; k += 2) {
        int2 se = csr[start + k];
        f32x4 ev = ef[(size_t)se.y * 32 + c];
        u32x2 hv = *(const u32x2*)(nfb + (size_t)se.x * D2 + 2 * c);
        ae[0] += ev[0];
        ae[1] += ev[1];
        ae[2] += ev[2];
        ae[3] += ev[3];
        ah[0] += bf_lo(hv.x);
        ah[1] += bf_hi(hv.x);
        ah[2] += bf_lo(hv.y);
        ah[3] += bf_hi(hv.y);
    }
    // combine the two halves
#pragma unroll
    for (int i = 0; i < 4; ++i) {
        ae[i] += __shfl_xor(ae[i], 32);
        ah[i] += __shfl_xor(ah[i], 32);
    }
    float inv = 1.0f / fmaxf((float)cnt, 1.0f);
    if (half == 0) {
        u32x2 eo;
        eo.x = pack_bf2(ae[0], ae[1]);
        eo.y = pack_bf2(ae[2], ae[3]);
        *(u32x2*)(efsum + (size_t)node * D2 + 2 * c) = eo;
    } else {
        u32x2 po;
        po.x = pack_bf2((ah[0] + ae[0]) * inv, (ah[1] + ae[1]) * inv);
        po.y = pack_bf2((ah[2] + ae[2]) * inv, (ah[3] + ae[3]) * inv);
        *(u32x2*)(pre + (size_t)node * D2 + 2 * c) = po;
    }
}

// ---------------- layer-2 aggregation: 4 edges/iteration ----------------
// quarter-wave (16 lanes) per edge; lane covers element group [8g, 8g+8).

__global__ void k_agg2(const unsigned int* __restrict__ h,  // h1 bf16 [N*64]
                       const int2* __restrict__ csr,
                       const int* __restrict__ offs, const int* __restrict__ deg,
                       const unsigned int* __restrict__ efsum,
                       unsigned int* __restrict__ pre) {
    int node = blockIdx.x * 4 + (threadIdx.x >> 6);
    if (node >= N_NODES) return;
    int lane = threadIdx.x & 63;
    int q = lane >> 4;  // which edge of the quad
    int g = lane & 15;  // element group [8g, 8g+8)
    int start = offs[node];
    int cnt = deg[node];
    float a[8] = {0.f, 0.f, 0.f, 0.f, 0.f, 0.f, 0.f, 0.f};
#pragma unroll 2
    for (int k = q; k < cnt; k += 4) {
        int2 se = csr[start + k];
        u32x4 hv = *(const u32x4*)(h + (size_t)se.x * D2 + 4 * g);
        a[0] += bf_lo(hv.x);
        a[1] += bf_hi(hv.x);
        a[2] += bf_lo(hv.y);
        a[3] += bf_hi(hv.y);
        a[4] += bf_lo(hv.z);
        a[5] += bf_hi(hv.z);
        a[6] += bf_lo(hv.w);
        a[7] += bf_hi(hv.w);
    }
    // combine the four quarters
#pragma unroll
    for (int i = 0; i < 8; ++i) {
        a[i] += __shfl_xor(a[i], 16);
        a[i] += __shfl_xor(a[i], 32);
    }
    if (q == 0) {
        u32x4 es = *(const u32x4*)(efsum + (size_t)node * D2 + 4 * g);
        float inv = 1.0f / fmaxf((float)cnt, 1.0f);
        float r0 = (a[0] + bf_lo(es.x)) * inv;
        float r1 = (a[1] + bf_hi(es.x)) * inv;
        float r2 = (a[2] + bf_lo(es.y)) * inv;
        float r3 = (a[3] + bf_hi(es.y)) * inv;
        float r4 = (a[4] + bf_lo(es.z)) * inv;
        float r5 = (a[5] + bf_hi(es.z)) * inv;
        float r6 = (a[6] + bf_lo(es.w)) * inv;
        float r7 = (a[7] + bf_hi(es.w)) * inv;
        u32x4 o;
        o.x = pack_bf2(r0, r1);
        o.y = pack_bf2(r2, r3);
        o.z = pack_bf2(r4, r5);
        o.w = pack_bf2(r6, r7);
        *(u32x4*)(pre + (size_t)node * D2 + 4 * g) = o;
    }
}

// ---------------- fused GEMM: out = leaky(pre@Wn^T + h@Ws^T) ----------------
// NT GEMM, M=50000, N=128, K=256 ([pre|h] @ [Wn|Ws]^T). All operands bf16.

template <int OUT_F32>
__global__ void k_gemm(const unsigned short* __restrict__ A1,  // pre [M,128] bf16
                       const unsigned short* __restrict__ A2,  // h   [M,128] bf16
                       const unsigned short* __restrict__ W1,  // Wn bf16
                       const unsigned short* __restrict__ W2,  // Ws bf16
                       void* __restrict__ outv) {
    int wave = threadIdx.x >> 6;
    int lane = threadIdx.x & 63;
    int quad = lane >> 4;
    int r16 = lane & 15;
    int m0 = (blockIdx.x * 4 + wave) * 32;  // 32 rows per wave (2 m-tiles)

    f32x4 acc[2][8];
#pragma unroll
    for (int mt = 0; mt < 2; ++mt)
#pragma unroll
        for (int nt = 0; nt < 8; ++nt) acc[mt][nt] = (f32x4){0.f, 0.f, 0.f, 0.f};

    int rowA0 = min(m0 + r16, N_NODES - 1);
    int rowA1 = min(m0 + 16 + r16, N_NODES - 1);

#pragma unroll
    for (int ks = 0; ks < 8; ++ks) {
        int koff = (ks & 3) * 32 + quad * 8;  // lane's 8 contiguous k
        const unsigned short* Asrc = (ks < 4) ? A1 : A2;
        bf16x8 a0 = *(const bf16x8*)(Asrc + (size_t)rowA0 * D + koff);
        bf16x8 a1 = *(const bf16x8*)(Asrc + (size_t)rowA1 * D + koff);
        const unsigned short* Wsrc = (ks < 4) ? W1 : W2;
#pragma unroll
        for (int nt = 0; nt < 8; ++nt) {
            bf16x8 b = *(const bf16x8*)(Wsrc + (size_t)(nt * 16 + r16) * D + koff);
            acc[0][nt] = __builtin_amdgcn_mfma_f32_16x16x32_bf16(a0, b, acc[0][nt], 0, 0, 0);
            acc[1][nt] = __builtin_amdgcn_mfma_f32_16x16x32_bf16(a1, b, acc[1][nt], 0, 0, 0);
        }
    }

    // C/D layout: col = lane&15, row = quad*4 + reg (m89/m91-verified)
#pragma unroll
    for (int mt = 0; mt < 2; ++mt) {
#pragma unroll
        for (int r = 0; r < 4; ++r) {
            int row = m0 + mt * 16 + quad * 4 + r;
            if (row < N_NODES) {
#pragma unroll
                for (int nt = 0; nt < 8; ++nt) {
                    float x = acc[mt][nt][r];
                    x = (x >= 0.f) ? x : x * SLOPE;
                    if (OUT_F32)
                        ((float*)outv)[(size_t)row * D + nt * 16 + r16] = x;
                    else
                        ((unsigned short*)outv)[(size_t)row * D + nt * 16 + r16] = f2bf(x);
                }
            }
        }
    }
}

// iso nodes (deg==0): out[n] = leaky(h[n] @ Wi^T), overwriting the GEMM value.
// Driven by the iso list; expected empty, so these are ~free.

__global__ void k_fixup1(const unsigned int* __restrict__ nfb,  // node_feats bf16
                         const float* __restrict__ Wi,          // fp32
                         const int* __restrict__ isolist, const int* __restrict__ niso,
                         unsigned short* __restrict__ out) {  // h1 bf16
    int w = blockIdx.x * 4 + (threadIdx.x >> 6);
    int lane = threadIdx.x & 63;
    int n = *niso;
    for (int t = w; t < n; t += gridDim.x * 4) {
        int node = isolist[t];
        const unsigned int* hrow = nfb + (size_t)node * D2;
        float a0 = 0.f, a1 = 0.f;
        for (int ku = 0; ku < D2; ++ku) {
            unsigned int v = hrow[ku];
            float h0 = bf_lo(v), h1 = bf_hi(v);
            a0 += h0 * Wi[(size_t)lane * D + 2 * ku] + h1 * Wi[(size_t)lane * D + 2 * ku + 1];
            a1 += h0 * Wi[(size_t)(lane + 64) * D + 2 * ku] +
                  h1 * Wi[(size_t)(lane + 64) * D + 2 * ku + 1];
        }
        a0 = (a0 >= 0.f) ? a0 : a0 * SLOPE;
        a1 = (a1 >= 0.f) ? a1 : a1 * SLOPE;
        out[(size_t)node * D + lane] = f2bf(a0);
        out[(size_t)node * D + lane + 64] = f2bf(a1);
    }
}

__global__ void k_fixup2(const unsigned short* __restrict__ h,  // h1 bf16
                         const float* __restrict__ Wi,          // fp32
                         const int* __restrict__ isolist, const int* __restrict__ niso,
                         float* __restrict__ out) {  // d_out fp32
    int w = blockIdx.x * 4 + (threadIdx.x >> 6);
    int lane = threadIdx.x & 63;
    int n = *niso;
    for (int t = w; t < n; t += gridDim.x * 4) {
        int node = isolist[t];
        const unsigned short* hrow = h + (size_t)node * D;
        float a0 = 0.f, a1 = 0.f;
        for (int k = 0; k < D; ++k) {
            float hk = __uint_as_float(((unsigned int)hrow[k]) << 16);
            a0 += hk * Wi[(size_t)lane * D + k];
            a1 += hk * Wi[(size_t)(lane + 64) * D + k];
        }
        a0 = (a0 >= 0.f) ? a0 : a0 * SLOPE;
        a1 = (a1 >= 0.f) ? a1 : a1 * SLOPE;
        out[(size_t)node * D + lane] = a0;
        out[(size_t)node * D + lane + 64] = a1;
    }
}

// ---------------- launch ----------------

extern "C" void kernel_launch(void* const* d_in, const int* in_sizes, int n_in,
                              void* d_out, int out_size, void* d_ws, size_t ws_size,
                              hipStream_t stream) {
    const float* node_feats = (const float*)d_in[0];
    const float* edge_feats = (const float*)d_in[1];
    const int* src = (const int*)d_in[2];
    const int* dst = (const int*)d_in[3];
    const float* Wn0 = (const float*)d_in[4];
    const float* Ws0 = (const float*)d_in[5];
    const float* Wi0 = (const float*)d_in[6];
    const float* Wn1 = (const float*)d_in[7];
    const float* Ws1 = (const float*)d_in[8];
    const float* Wi1 = (const float*)d_in[9];

    char* ws = (char*)d_ws;
    size_t o = 0;
    auto alloc = [&](size_t bytes) -> char* {
        char* p = ws + o;
        o += (bytes + 255) & ~size_t(255);
        return p;
    };
    int* deg = (int*)alloc((size_t)N_NODES * 4);   // 200192 B
    int* cur = (int*)alloc((size_t)N_NODES * 4);   // 200192 B
    int* niso = (int*)alloc(256);                  // 256 B (zeroed with deg/cur)
    int* offs = (int*)alloc((size_t)N_NODES * 4);
    int* part = (int*)alloc(1024);
    int* isolist = (int*)alloc((size_t)N_NODES * 4);
    int2* csr = (int2*)alloc((size_t)N_EDGES * 8);                        //  6.4 MB
    unsigned int* efsum = (unsigned int*)alloc((size_t)N_NODES * D * 2);  // 12.8 MB
    unsigned int* pre = (unsigned int*)alloc((size_t)N_NODES * D * 2);    // 12.8 MB
    unsigned int* h1 = (unsigned int*)alloc((size_t)N_NODES * D * 2);     // 12.8 MB
    unsigned int* nfb = (unsigned int*)alloc((size_t)N_NODES * D * 2);    // 12.8 MB
    unsigned int* wbf = (unsigned int*)alloc(4 * 8192 * 4);               // 128 KB

    // zero deg + cur + niso (contiguous allocations)
    hipMemsetAsync(deg, 0, 2 * (((size_t)N_NODES * 4 + 255) & ~size_t(255)) + 256, stream);

    int ebl = (N_EDGES + 255) / 256;  // 3125
    int nbl = (N_NODES + 255) / 256;  // 196
    int nwb = (N_NODES + 3) / 4;      // 12500 (4 waves/block, wave-per-node)
    int gbl = (N_NODES + 127) / 128;  // 391 (128 rows/block)

    k_cvt_nf<<<(N_NODES * D / 8 + 255) / 256, 256, 0, stream>>>((const f32x4*)node_feats,
                                                                (u32x4*)nfb);
    k_cvt_w<<<32, 256, 0, stream>>>(Wn0, Ws0, Wn1, Ws1, wbf);
    k_count<<<ebl, 256, 0, stream>>>(dst, deg);
    k_scan1<<<nbl, 256, 0, stream>>>(deg, offs, part);
    k_scan2<<<1, 256, 0, stream>>>(part, nbl);
    k_scan3<<<nbl, 256, 0, stream>>>(offs, part);
    k_fill<<<ebl, 256, 0, stream>>>(src, dst, offs, cur, csr);
    k_iso<<<nbl, 256, 0, stream>>>(deg, isolist, niso);

    const unsigned short* Wn0b = (const unsigned short*)(wbf + 0 * 8192);
    const unsigned short* Ws0b = (const unsigned short*)(wbf + 1 * 8192);
    const unsigned short* Wn1b = (const unsigned short*)(wbf + 2 * 8192);
    const unsigned short* Ws1b = (const unsigned short*)(wbf + 3 * 8192);

    // layer 1: nfb (bf16) -> h1 (bf16); also builds efsum (bf16)
    k_agg_ef<<<nwb, 256, 0, stream>>>(nfb, (const f32x4*)edge_feats, csr, offs, deg, efsum, pre);
    k_gemm<0><<<gbl, 256, 0, stream>>>((const unsigned short*)pre, (const unsigned short*)nfb,
                                       Wn0b, Ws0b, (void*)h1);
    k_fixup1<<<32, 256, 0, stream>>>(nfb, Wi0, isolist, niso, (unsigned short*)h1);

    // layer 2: h1 (bf16) -> d_out (fp32)
    k_agg2<<<nwb, 256, 0, stream>>>(h1, csr, offs, deg, efsum, pre);
    k_gemm<1><<<gbl, 256, 0, stream>>>((const unsigned short*)pre, (const unsigned short*)h1,
                                       Wn1b, Ws1b, d_out);
    k_fixup2<<<32, 256, 0, stream>>>((const unsigned short*)h1, Wi1, isolist, niso, (float*)d_out);
}